// Round 3
// baseline (462.230 us; speedup 1.0000x reference)
//
#include <hip/hip_runtime.h>
#include <hip/hip_bf16.h>

#define D 64
#define NUM_LAYERS 4
#define TILE 4096
#define EPT 16          // edges per thread in placeA (256 thr * 16 = TILE)
#define BKMAX 320       // max buckets (N <= 163840)

// ---------------- helpers ----------------

__device__ __forceinline__ float bf_lo(unsigned u) { return __uint_as_float(u << 16); }
__device__ __forceinline__ float bf_hi(unsigned u) { return __uint_as_float(u & 0xffff0000u); }
__device__ __forceinline__ unsigned bf_pack(float x, float y) {
    __hip_bfloat16 bx = __float2bfloat16(x);
    __hip_bfloat16 by = __float2bfloat16(y);
    return (unsigned)(*reinterpret_cast<unsigned short*>(&bx))
         | ((unsigned)(*reinterpret_cast<unsigned short*>(&by)) << 16);
}

// ---------------- bucket histogram (+ per-node degree) + scan ----------------

__global__ void bhist_kernel(const int* __restrict__ dst, int* __restrict__ bcnt,
                             int* __restrict__ deg, int E, int nbk) {
    __shared__ int h[BKMAX];
    for (int i = threadIdx.x; i < nbk; i += blockDim.x) h[i] = 0;
    __syncthreads();
    int stride = gridDim.x * blockDim.x;
    int gid = blockIdx.x * blockDim.x + threadIdx.x;
    // vectorized main body (dst 16B-aligned when E%4==0; fallback otherwise)
    int E4 = (((size_t)dst & 15) == 0) ? (E >> 2) : 0;
    const int4* dst4 = (const int4*)dst;
    for (int i = gid; i < E4; i += stride) {
        int4 d = dst4[i];
        atomicAdd(&h[d.x >> 9], 1); atomicAdd(&deg[d.x], 1);
        atomicAdd(&h[d.y >> 9], 1); atomicAdd(&deg[d.y], 1);
        atomicAdd(&h[d.z >> 9], 1); atomicAdd(&deg[d.z], 1);
        atomicAdd(&h[d.w >> 9], 1); atomicAdd(&deg[d.w], 1);
    }
    for (int e = (E4 << 2) + gid; e < E; e += stride) {
        int d = dst[e];
        atomicAdd(&h[d >> 9], 1); atomicAdd(&deg[d], 1);
    }
    __syncthreads();
    for (int i = threadIdx.x; i < nbk; i += blockDim.x)
        if (h[i] > 0) atomicAdd(&bcnt[i], h[i]);
}

// single block: exclusive scan of bucket counts -> bstart, gcur
__global__ __launch_bounds__(512) void bscan_kernel(const int* __restrict__ bcnt,
                                                    int* __restrict__ bstart,
                                                    int* __restrict__ gcur, int nbk, int E) {
    __shared__ int sm[512];
    int t = threadIdx.x;
    int v = (t < nbk) ? bcnt[t] : 0;
    sm[t] = v;
    __syncthreads();
    for (int ofs = 1; ofs < 512; ofs <<= 1) {
        int x = (t >= ofs) ? sm[t - ofs] : 0;
        __syncthreads();
        sm[t] += x;
        __syncthreads();
    }
    int excl = sm[t] - v;
    if (t < nbk) { bstart[t] = excl; gcur[t] = excl; }
    if (t == 0) bstart[nbk] = E;
}

// ---------------- place: two-phase tile-partitioned counting sort ----------------

// Pass A: tile -> bucket-sorted mid. Payload: src | (dst&511)<<18  (27 bits, 4B)
__global__ __launch_bounds__(256) void placeA_kernel(const int* __restrict__ src,
                                                     const int* __restrict__ dst,
                                                     int* __restrict__ gcur,
                                                     int* __restrict__ mid,
                                                     int E, int nbk) {
    __shared__ int hist[BKMAX];
    __shared__ int gbase[BKMAX];
    int t = threadIdx.x;
    int tile0 = blockIdx.x * TILE;
    for (int i = t; i < nbk; i += 256) hist[i] = 0;
    __syncthreads();

    bool al = (((size_t)src & 15) == 0) && (((size_t)dst & 15) == 0);

    int p_[EPT];
    int b_[EPT];
    int r_[EPT];
#pragma unroll
    for (int i4 = 0; i4 < 4; ++i4) {
        int e0 = tile0 + i4 * 1024 + t * 4;   // thread handles 4 consecutive edges
        int4 s4, d4;
        if (al && (e0 + 3 < E)) {
            s4 = *(const int4*)(src + e0);
            d4 = *(const int4*)(dst + e0);
        } else {
            s4 = make_int4(0, 0, 0, 0); d4 = make_int4(0, 0, 0, 0);
            if (e0     < E) { s4.x = src[e0];     d4.x = dst[e0]; }
            if (e0 + 1 < E) { s4.y = src[e0 + 1]; d4.y = dst[e0 + 1]; }
            if (e0 + 2 < E) { s4.z = src[e0 + 2]; d4.z = dst[e0 + 2]; }
            if (e0 + 3 < E) { s4.w = src[e0 + 3]; d4.w = dst[e0 + 3]; }
        }
        int ss[4] = { s4.x, s4.y, s4.z, s4.w };
        int dd[4] = { d4.x, d4.y, d4.z, d4.w };
#pragma unroll
        for (int k = 0; k < 4; ++k) {
            int i = i4 * 4 + k;
            int e = e0 + k;
            b_[i] = -1;
            if (e < E) {
                p_[i] = ss[k] | ((dd[k] & 511) << 18);
                b_[i] = dd[k] >> 9;
                r_[i] = atomicAdd(&hist[b_[i]], 1);
            }
        }
    }
    __syncthreads();
    for (int b = t; b < nbk; b += 256) {
        int h = hist[b];
        gbase[b] = (h > 0) ? atomicAdd(&gcur[b], h) : 0;
    }
    __syncthreads();
#pragma unroll
    for (int i = 0; i < EPT; ++i) {
        if (b_[i] >= 0) mid[gbase[b_[i]] + r_[i]] = p_[i];
    }
}

// Fused pass B: one block per bucket. Coalesced deg reads -> LDS scan ->
// row_start; then weighted scatter (w from rsqrt(deg) on the fly).
__global__ __launch_bounds__(512) void placeB_kernel(const int* __restrict__ bstart,
                                                     const int* __restrict__ mid,
                                                     const int* __restrict__ deg,
                                                     int* __restrict__ row_start,
                                                     int2* __restrict__ csr,
                                                     int N, int nbk, int E) {
    __shared__ int sc[512];
    __shared__ int cur[512];
    __shared__ float dloc[512];
    int b = blockIdx.x;
    int t = threadIdx.x;
    int node0 = b << 9;
    int node = node0 + t;
    int lo = bstart[b], hi = bstart[b + 1];
    int d = (node < N) ? deg[node] : 0;
    sc[t] = d;
    __syncthreads();
    for (int ofs = 1; ofs < 512; ofs <<= 1) {
        int x = (t >= ofs) ? sc[t - ofs] : 0;
        __syncthreads();
        sc[t] += x;
        __syncthreads();
    }
    int excl = sc[t] - d;
    if (node < N) row_start[node] = lo + excl;
    cur[t] = lo + excl;
    dloc[t] = (d > 0) ? rsqrtf((float)d) : 0.0f;
    if (b == nbk - 1 && t == 0) row_start[N] = E;
    __syncthreads();
    for (int e = lo + t; e < hi; e += 512) {
        int m = mid[e];
        int l = (m >> 18) & 511;
        int s = m & 0x3FFFF;
        int dsv = deg[s];
        float w = ((dsv > 0) ? rsqrtf((float)dsv) : 0.0f) * dloc[l];
        int slot = atomicAdd(&cur[l], 1);
        csr[slot] = make_int2(s, __float_as_int(w));
    }
}

// ---------------- propagation ----------------

// 8 floats per thread: 2x float4 in, 1x uint4 (8 bf16) out.
__global__ void init_kernel(const float* __restrict__ users, const float* __restrict__ items,
                            unsigned* __restrict__ A, int nu_elems, int total8) {
    int i = blockIdx.x * blockDim.x + threadIdx.x;   // bf16x8 group index
    if (i >= total8) return;
    long long base = (long long)i * 8;
    const float4* p;
    if (base < nu_elems) p = (const float4*)users + (base >> 2);
    else                 p = (const float4*)items + ((base - nu_elems) >> 2);
    float4 a = p[0];
    float4 b = p[1];
    uint4 r;
    r.x = bf_pack(a.x, a.y);
    r.y = bf_pack(a.z, a.w);
    r.z = bf_pack(b.x, b.y);
    r.w = bf_pack(b.z, b.w);
    ((uint4*)A)[i] = r;
}

// One wave per dst node, quarter-wave per edge: q = lane>>4 picks the edge,
// c = lane&15 picks the bf16x4 (8B) chunk of the 128B row. 8 edges per iter.
template <int FINAL>
__global__ void gather_kernel(const int* __restrict__ row_start,
                              const int2* __restrict__ csr,
                              const uint2* __restrict__ Au,
                              uint2* __restrict__ Bu,
                              const float* __restrict__ users, const float* __restrict__ items,
                              const uint2* __restrict__ L1u, const uint2* __restrict__ L2u,
                              float* __restrict__ out,
                              int N, int nu) {
    int node = (blockIdx.x * blockDim.x + threadIdx.x) >> 6;
    if (node >= N) return;
    int lane = threadIdx.x & 63;
    int q = lane >> 4;
    int c = lane & 15;
    int beg = row_start[node];
    int end = row_start[node + 1];
    int deg = end - beg;
    float ax = 0.0f, ay = 0.0f, az = 0.0f, aw = 0.0f;

    for (int base = 0; base < deg; base += 64) {
        int chunk = min(64, deg - base);
        int   sl = 0;
        float wl = 0.0f;
        if (lane < chunk) {
            int2 e = csr[beg + base + lane];
            sl = e.x;
            wl = __int_as_float(e.y);
        }
        int k = 0;
        for (; k + 8 <= chunk; k += 8) {
            int i0 = k + q, i1 = k + 4 + q;
            int   s0 = __shfl(sl, i0), s1 = __shfl(sl, i1);
            float w0 = __shfl(wl, i0), w1 = __shfl(wl, i1);
            uint2 u0 = Au[(size_t)s0 * 16 + c];
            uint2 u1 = Au[(size_t)s1 * 16 + c];
            ax += w0 * bf_lo(u0.x); ay += w0 * bf_hi(u0.x);
            az += w0 * bf_lo(u0.y); aw += w0 * bf_hi(u0.y);
            ax += w1 * bf_lo(u1.x); ay += w1 * bf_hi(u1.x);
            az += w1 * bf_lo(u1.y); aw += w1 * bf_hi(u1.y);
        }
        for (; k < chunk; k += 4) {
            int i0 = k + q;
            int   s = __shfl(sl, i0);
            float w = __shfl(wl, i0);
            uint2 u = Au[(size_t)s * 16 + c];
            ax += w * bf_lo(u.x); ay += w * bf_hi(u.x);
            az += w * bf_lo(u.y); aw += w * bf_hi(u.y);
        }
    }

    ax += __shfl_xor(ax, 16); ay += __shfl_xor(ay, 16);
    az += __shfl_xor(az, 16); aw += __shfl_xor(aw, 16);
    ax += __shfl_xor(ax, 32); ay += __shfl_xor(ay, 32);
    az += __shfl_xor(az, 32); aw += __shfl_xor(aw, 32);

    if (q == 0) {
        size_t ro = (size_t)node * 16 + c;
        if (FINAL) {
            uint2 l1 = L1u[ro], l2 = L2u[ro], l3 = Au[ro];
            float4 e0;
            if (node < nu) e0 = ((const float4*)users)[ro];
            else           e0 = ((const float4*)items)[(size_t)(node - nu) * 16 + c];
            float rx = (e0.x + bf_lo(l1.x) + bf_lo(l2.x) + bf_lo(l3.x) + ax) * 0.04f;
            float ry = (e0.y + bf_hi(l1.x) + bf_hi(l2.x) + bf_hi(l3.x) + ay) * 0.04f;
            float rz = (e0.z + bf_lo(l1.y) + bf_lo(l2.y) + bf_lo(l3.y) + az) * 0.04f;
            float rw = (e0.w + bf_hi(l1.y) + bf_hi(l2.y) + bf_hi(l3.y) + aw) * 0.04f;
            ((float4*)out)[ro] = make_float4(rx, ry, rz, rw);
        } else {
            uint2 p;
            p.x = bf_pack(ax, ay);
            p.y = bf_pack(az, aw);
            Bu[ro] = p;
        }
    }
}

// ---------------- launch ----------------

extern "C" void kernel_launch(void* const* d_in, const int* in_sizes, int n_in,
                              void* d_out, int out_size, void* d_ws, size_t ws_size,
                              hipStream_t stream) {
    const float* users = (const float*)d_in[0];
    const float* items = (const float*)d_in[1];
    const int*   eidx  = (const int*)d_in[2];

    const int nu = in_sizes[0] / D;    // 100000
    const int ni = in_sizes[1] / D;    // 50000
    const int N  = nu + ni;            // 150000
    const int E  = in_sizes[2] / 2;    // 2000000
    const int Nf = N * D;              // 9.6M elems
    const int nbk = (N + 511) >> 9;    // 293 buckets

    const int* src = eidx;
    const int* dst = eidx + E;

    char* ws = (char*)d_ws;
    size_t off = 0;
    auto alloc = [&](size_t bytes) {
        char* p = ws + off;
        off += (bytes + 255) & ~(size_t)255;
        return p;
    };
    int*   row_start = (int*)alloc((size_t)(N + 1) * 4);
    int*   bcnt      = (int*)alloc(BKMAX * 4 + (size_t)N * 4);  // bcnt + deg contiguous -> 1 memset
    int*   deg       = bcnt + BKMAX;
    int*   bstart    = (int*)alloc((BKMAX + 1) * 4);
    int*   gcur      = (int*)alloc(BKMAX * 4);
    int2*  csr       = (int2*)alloc((size_t)E * 8);
    unsigned* A0 = (unsigned*)alloc((size_t)Nf * 2);
    unsigned* L1 = (unsigned*)alloc((size_t)Nf * 2);
    unsigned* L2 = (unsigned*)alloc((size_t)Nf * 2);
    unsigned* L3 = (unsigned*)alloc((size_t)Nf * 2);
    int* mid = (int*)L3;   // alias: mid (E*4B) consumed before L3 is written (gather #3)

    const int B256 = 256;
    auto blocks = [](long long n, int b) { return (int)((n + b - 1) / b); };

    // 1. bucket histogram + per-node degree, then bucket scan
    hipMemsetAsync(bcnt, 0, BKMAX * 4 + (size_t)N * 4, stream);
    bhist_kernel<<<1024, B256, 0, stream>>>(dst, bcnt, deg, E, nbk);
    bscan_kernel<<<1, 512, 0, stream>>>(bcnt, bstart, gcur, nbk, E);

    // 2. place: tile-partition into buckets (4B payload), then fused per-bucket
    //    scan (row_start from deg) + weighted scatter
    placeA_kernel<<<blocks(E, TILE), B256, 0, stream>>>(src, dst, gcur, mid, E, nbk);
    placeB_kernel<<<nbk, 512, 0, stream>>>(bstart, mid, deg, row_start, csr, N, nbk, E);

    // 3. init bf16 A0
    init_kernel<<<blocks(Nf / 8, B256), B256, 0, stream>>>(users, items, A0, nu * D, Nf / 8);

    // 4. propagation: wave per node; L1..L3 bf16; layer 4 fused with final
    //    combine -> f32 d_out
    const int ggrid = blocks(N, B256 / 64);
    gather_kernel<0><<<ggrid, B256, 0, stream>>>(row_start, csr, (const uint2*)A0, (uint2*)L1,
                                                 nullptr, nullptr, nullptr, nullptr, nullptr, N, nu);
    gather_kernel<0><<<ggrid, B256, 0, stream>>>(row_start, csr, (const uint2*)L1, (uint2*)L2,
                                                 nullptr, nullptr, nullptr, nullptr, nullptr, N, nu);
    gather_kernel<0><<<ggrid, B256, 0, stream>>>(row_start, csr, (const uint2*)L2, (uint2*)L3,
                                                 nullptr, nullptr, nullptr, nullptr, nullptr, N, nu);
    gather_kernel<1><<<ggrid, B256, 0, stream>>>(row_start, csr, (const uint2*)L3, nullptr,
                                                 users, items, (const uint2*)L1, (const uint2*)L2,
                                                 (float*)d_out, N, nu);
}

// Round 4
// 419.320 us; speedup vs baseline: 1.1023x; 1.1023x over previous
//
#include <hip/hip_runtime.h>
#include <hip/hip_bf16.h>

#define D 64
#define NUM_LAYERS 4
#define TILE 4096
#define EPT 16          // edges per thread in placeA (256 thr * 16 = TILE)
#define BKMAX 320       // max buckets (N <= 163840)

// ---------------- helpers ----------------

__device__ __forceinline__ float bf_lo(unsigned u) { return __uint_as_float(u << 16); }
__device__ __forceinline__ float bf_hi(unsigned u) { return __uint_as_float(u & 0xffff0000u); }
__device__ __forceinline__ unsigned bf_pack(float x, float y) {
    __hip_bfloat16 bx = __float2bfloat16(x);
    __hip_bfloat16 by = __float2bfloat16(y);
    return (unsigned)(*reinterpret_cast<unsigned short*>(&bx))
         | ((unsigned)(*reinterpret_cast<unsigned short*>(&by)) << 16);
}

// ---------------- bucket histogram + scan ----------------
// LDS-only histogram: per-node degrees are NOT computed here — 2M device-scope
// scatter atomics cost ~85us on gfx950 (cross-XCD coherence write-through;
// measured round 3). Degrees stay bucket-local in placeB1's LDS.

__global__ void bhist_kernel(const int* __restrict__ dst, int* __restrict__ bcnt, int E, int nbk) {
    __shared__ int h[BKMAX];
    for (int i = threadIdx.x; i < nbk; i += blockDim.x) h[i] = 0;
    __syncthreads();
    int stride = gridDim.x * blockDim.x;
    int gid = blockIdx.x * blockDim.x + threadIdx.x;
    int E4 = (((size_t)dst & 15) == 0) ? (E >> 2) : 0;
    const int4* dst4 = (const int4*)dst;
    for (int i = gid; i < E4; i += stride) {
        int4 d = dst4[i];
        atomicAdd(&h[d.x >> 9], 1);
        atomicAdd(&h[d.y >> 9], 1);
        atomicAdd(&h[d.z >> 9], 1);
        atomicAdd(&h[d.w >> 9], 1);
    }
    for (int e = (E4 << 2) + gid; e < E; e += stride)
        atomicAdd(&h[dst[e] >> 9], 1);
    __syncthreads();
    for (int i = threadIdx.x; i < nbk; i += blockDim.x)
        if (h[i] > 0) atomicAdd(&bcnt[i], h[i]);
}

// single block: exclusive scan of bucket counts -> bstart, gcur
__global__ __launch_bounds__(512) void bscan_kernel(const int* __restrict__ bcnt,
                                                    int* __restrict__ bstart,
                                                    int* __restrict__ gcur, int nbk, int E) {
    __shared__ int sm[512];
    int t = threadIdx.x;
    int v = (t < nbk) ? bcnt[t] : 0;
    sm[t] = v;
    __syncthreads();
    for (int ofs = 1; ofs < 512; ofs <<= 1) {
        int x = (t >= ofs) ? sm[t - ofs] : 0;
        __syncthreads();
        sm[t] += x;
        __syncthreads();
    }
    int excl = sm[t] - v;
    if (t < nbk) { bstart[t] = excl; gcur[t] = excl; }
    if (t == 0) bstart[nbk] = E;
}

// ---------------- place: two-phase tile-partitioned counting sort ----------------

// Pass A: tile -> bucket-sorted mid. Payload: src | (dst&511)<<18  (27 bits, 4B)
__global__ __launch_bounds__(256) void placeA_kernel(const int* __restrict__ src,
                                                     const int* __restrict__ dst,
                                                     int* __restrict__ gcur,
                                                     int* __restrict__ mid,
                                                     int E, int nbk) {
    __shared__ int hist[BKMAX];
    __shared__ int gbase[BKMAX];
    int t = threadIdx.x;
    int tile0 = blockIdx.x * TILE;
    for (int i = t; i < nbk; i += 256) hist[i] = 0;
    __syncthreads();

    bool al = (((size_t)src & 15) == 0) && (((size_t)dst & 15) == 0);

    int p_[EPT];
    int b_[EPT];
    int r_[EPT];
#pragma unroll
    for (int i4 = 0; i4 < 4; ++i4) {
        int e0 = tile0 + i4 * 1024 + t * 4;   // thread handles 4 consecutive edges
        int4 s4, d4;
        if (al && (e0 + 3 < E)) {
            s4 = *(const int4*)(src + e0);
            d4 = *(const int4*)(dst + e0);
        } else {
            s4 = make_int4(0, 0, 0, 0); d4 = make_int4(0, 0, 0, 0);
            if (e0     < E) { s4.x = src[e0];     d4.x = dst[e0]; }
            if (e0 + 1 < E) { s4.y = src[e0 + 1]; d4.y = dst[e0 + 1]; }
            if (e0 + 2 < E) { s4.z = src[e0 + 2]; d4.z = dst[e0 + 2]; }
            if (e0 + 3 < E) { s4.w = src[e0 + 3]; d4.w = dst[e0 + 3]; }
        }
        int ss[4] = { s4.x, s4.y, s4.z, s4.w };
        int dd[4] = { d4.x, d4.y, d4.z, d4.w };
#pragma unroll
        for (int k = 0; k < 4; ++k) {
            int i = i4 * 4 + k;
            int e = e0 + k;
            b_[i] = -1;
            if (e < E) {
                p_[i] = ss[k] | ((dd[k] & 511) << 18);
                b_[i] = dd[k] >> 9;
                r_[i] = atomicAdd(&hist[b_[i]], 1);
            }
        }
    }
    __syncthreads();
    for (int b = t; b < nbk; b += 256) {
        int h = hist[b];
        gbase[b] = (h > 0) ? atomicAdd(&gcur[b], h) : 0;
    }
    __syncthreads();
#pragma unroll
    for (int i = 0; i < EPT; ++i) {
        if (b_[i] >= 0) mid[gbase[b_[i]] + r_[i]] = p_[i];
    }
}

// Pass B1: one block per bucket; per-node degree count in LDS, LDS scan ->
// row_start + deg_inv_sqrt for this bucket's 512 nodes.
__global__ __launch_bounds__(512) void placeB1_kernel(const int* __restrict__ bstart,
                                                      const int* __restrict__ mid,
                                                      int* __restrict__ row_start,
                                                      float* __restrict__ dis,
                                                      int N, int nbk, int E) {
    __shared__ int degsm[512];
    __shared__ int sc[512];
    int b = blockIdx.x;
    int t = threadIdx.x;
    int node0 = b << 9;
    int lo = bstart[b], hi = bstart[b + 1];
    degsm[t] = 0;
    __syncthreads();
    for (int e = lo + t; e < hi; e += 512)
        atomicAdd(&degsm[(mid[e] >> 18) & 511], 1);
    __syncthreads();
    int d = degsm[t];
    sc[t] = d;
    __syncthreads();
    for (int ofs = 1; ofs < 512; ofs <<= 1) {
        int x = (t >= ofs) ? sc[t - ofs] : 0;
        __syncthreads();
        sc[t] += x;
        __syncthreads();
    }
    int excl = sc[t] - d;
    int node = node0 + t;
    if (node < N) {
        row_start[node] = lo + excl;
        dis[node] = (d > 0) ? rsqrtf((float)d) : 0.0f;
    }
    if (b == nbk - 1 && t == 0) row_start[N] = E;
}

// Pass B2: scatter within bucket; compute w = dis[src]*dis[dst] once here.
__global__ __launch_bounds__(512) void placeB2_kernel(const int* __restrict__ bstart,
                                                      const int* __restrict__ mid,
                                                      const int* __restrict__ row_start,
                                                      const float* __restrict__ dis,
                                                      int2* __restrict__ csr, int N) {
    __shared__ int cur[512];
    __shared__ float dloc[512];
    int b = blockIdx.x;
    int t = threadIdx.x;
    int node0 = b << 9;
    int node = node0 + t;
    if (node < N) { cur[t] = row_start[node]; dloc[t] = dis[node]; }
    else          { cur[t] = 0; dloc[t] = 0.0f; }
    __syncthreads();
    int lo = bstart[b], hi = bstart[b + 1];
    for (int e = lo + t; e < hi; e += 512) {
        int m = mid[e];
        int l = (m >> 18) & 511;
        int s = m & 0x3FFFF;
        float w = dis[s] * dloc[l];
        int slot = atomicAdd(&cur[l], 1);
        csr[slot] = make_int2(s, __float_as_int(w));
    }
}

// ---------------- propagation ----------------

// 8 floats per thread: 2x float4 in, 1x uint4 (8 bf16) out.
__global__ void init_kernel(const float* __restrict__ users, const float* __restrict__ items,
                            unsigned* __restrict__ A, int nu_elems, int total8) {
    int i = blockIdx.x * blockDim.x + threadIdx.x;   // bf16x8 group index
    if (i >= total8) return;
    long long base = (long long)i * 8;
    const float4* p;
    if (base < nu_elems) p = (const float4*)users + (base >> 2);
    else                 p = (const float4*)items + ((base - nu_elems) >> 2);
    float4 a = p[0];
    float4 b = p[1];
    uint4 r;
    r.x = bf_pack(a.x, a.y);
    r.y = bf_pack(a.z, a.w);
    r.z = bf_pack(b.x, b.y);
    r.w = bf_pack(b.z, b.w);
    ((uint4*)A)[i] = r;
}

// One wave per dst node, quarter-wave per edge: q = lane>>4 picks the edge,
// c = lane&15 picks the bf16x4 (8B) chunk of the 128B row. 8 edges per iter.
// csr is streamed once per dispatch -> nontemporal, keeps L2 for the reused
// embedding rows.
template <int FINAL>
__global__ void gather_kernel(const int* __restrict__ row_start,
                              const int2* __restrict__ csr,
                              const uint2* __restrict__ Au,
                              uint2* __restrict__ Bu,
                              const float* __restrict__ users, const float* __restrict__ items,
                              const uint2* __restrict__ L1u, const uint2* __restrict__ L2u,
                              float* __restrict__ out,
                              int N, int nu) {
    int node = (blockIdx.x * blockDim.x + threadIdx.x) >> 6;
    if (node >= N) return;
    int lane = threadIdx.x & 63;
    int q = lane >> 4;
    int c = lane & 15;
    int beg = row_start[node];
    int end = row_start[node + 1];
    int deg = end - beg;
    float ax = 0.0f, ay = 0.0f, az = 0.0f, aw = 0.0f;

    for (int base = 0; base < deg; base += 64) {
        int chunk = min(64, deg - base);
        int   sl = 0;
        float wl = 0.0f;
        if (lane < chunk) {
            long long p = __builtin_nontemporal_load((const long long*)(csr + beg + base + lane));
            sl = (int)(p & 0xFFFFFFFFLL);
            wl = __int_as_float((int)(p >> 32));
        }
        int k = 0;
        for (; k + 8 <= chunk; k += 8) {
            int i0 = k + q, i1 = k + 4 + q;
            int   s0 = __shfl(sl, i0), s1 = __shfl(sl, i1);
            float w0 = __shfl(wl, i0), w1 = __shfl(wl, i1);
            uint2 u0 = Au[(size_t)s0 * 16 + c];
            uint2 u1 = Au[(size_t)s1 * 16 + c];
            ax += w0 * bf_lo(u0.x); ay += w0 * bf_hi(u0.x);
            az += w0 * bf_lo(u0.y); aw += w0 * bf_hi(u0.y);
            ax += w1 * bf_lo(u1.x); ay += w1 * bf_hi(u1.x);
            az += w1 * bf_lo(u1.y); aw += w1 * bf_hi(u1.y);
        }
        for (; k < chunk; k += 4) {
            int i0 = k + q;
            int   s = __shfl(sl, i0);
            float w = __shfl(wl, i0);
            uint2 u = Au[(size_t)s * 16 + c];
            ax += w * bf_lo(u.x); ay += w * bf_hi(u.x);
            az += w * bf_lo(u.y); aw += w * bf_hi(u.y);
        }
    }

    ax += __shfl_xor(ax, 16); ay += __shfl_xor(ay, 16);
    az += __shfl_xor(az, 16); aw += __shfl_xor(aw, 16);
    ax += __shfl_xor(ax, 32); ay += __shfl_xor(ay, 32);
    az += __shfl_xor(az, 32); aw += __shfl_xor(aw, 32);

    if (q == 0) {
        size_t ro = (size_t)node * 16 + c;
        if (FINAL) {
            uint2 l1;
            l1.x = __builtin_nontemporal_load(&L1u[ro].x);
            l1.y = __builtin_nontemporal_load(&L1u[ro].y);
            uint2 l2;
            l2.x = __builtin_nontemporal_load(&L2u[ro].x);
            l2.y = __builtin_nontemporal_load(&L2u[ro].y);
            uint2 l3 = Au[ro];
            float4 e0;
            if (node < nu) e0 = ((const float4*)users)[ro];
            else           e0 = ((const float4*)items)[(size_t)(node - nu) * 16 + c];
            float rx = (e0.x + bf_lo(l1.x) + bf_lo(l2.x) + bf_lo(l3.x) + ax) * 0.04f;
            float ry = (e0.y + bf_hi(l1.x) + bf_hi(l2.x) + bf_hi(l3.x) + ay) * 0.04f;
            float rz = (e0.z + bf_lo(l1.y) + bf_lo(l2.y) + bf_lo(l3.y) + az) * 0.04f;
            float rw = (e0.w + bf_hi(l1.y) + bf_hi(l2.y) + bf_hi(l3.y) + aw) * 0.04f;
            ((float4*)out)[ro] = make_float4(rx, ry, rz, rw);
        } else {
            uint2 p;
            p.x = bf_pack(ax, ay);
            p.y = bf_pack(az, aw);
            Bu[ro] = p;
        }
    }
}

// ---------------- launch ----------------

extern "C" void kernel_launch(void* const* d_in, const int* in_sizes, int n_in,
                              void* d_out, int out_size, void* d_ws, size_t ws_size,
                              hipStream_t stream) {
    const float* users = (const float*)d_in[0];
    const float* items = (const float*)d_in[1];
    const int*   eidx  = (const int*)d_in[2];

    const int nu = in_sizes[0] / D;    // 100000
    const int ni = in_sizes[1] / D;    // 50000
    const int N  = nu + ni;            // 150000
    const int E  = in_sizes[2] / 2;    // 2000000
    const int Nf = N * D;              // 9.6M elems
    const int nbk = (N + 511) >> 9;    // 293 buckets

    const int* src = eidx;
    const int* dst = eidx + E;

    char* ws = (char*)d_ws;
    size_t off = 0;
    auto alloc = [&](size_t bytes) {
        char* p = ws + off;
        off += (bytes + 255) & ~(size_t)255;
        return p;
    };
    float* dis       = (float*)alloc((size_t)N * 4);
    int*   row_start = (int*)alloc((size_t)(N + 1) * 4);
    int*   bcnt      = (int*)alloc(BKMAX * 4);
    int*   bstart    = (int*)alloc((BKMAX + 1) * 4);
    int*   gcur      = (int*)alloc(BKMAX * 4);
    int2*  csr       = (int2*)alloc((size_t)E * 8);
    unsigned* A0 = (unsigned*)alloc((size_t)Nf * 2);
    unsigned* L1 = (unsigned*)alloc((size_t)Nf * 2);
    unsigned* L2 = (unsigned*)alloc((size_t)Nf * 2);
    unsigned* L3 = (unsigned*)alloc((size_t)Nf * 2);
    int* mid = (int*)L3;   // alias: mid (E*4B) consumed before L3 is written (gather #3)

    const int B256 = 256;
    auto blocks = [](long long n, int b) { return (int)((n + b - 1) / b); };

    // 1. bucket histogram + bucket scan
    hipMemsetAsync(bcnt, 0, BKMAX * 4, stream);
    bhist_kernel<<<1024, B256, 0, stream>>>(dst, bcnt, E, nbk);
    bscan_kernel<<<1, 512, 0, stream>>>(bcnt, bstart, gcur, nbk, E);

    // 2. place: tile-partition into buckets (4B payload), then per-bucket
    //    degree count + scan (B1) and weighted scatter (B2)
    placeA_kernel<<<blocks(E, TILE), B256, 0, stream>>>(src, dst, gcur, mid, E, nbk);
    placeB1_kernel<<<nbk, 512, 0, stream>>>(bstart, mid, row_start, dis, N, nbk, E);
    placeB2_kernel<<<nbk, 512, 0, stream>>>(bstart, mid, row_start, dis, csr, N);

    // 3. init bf16 A0
    init_kernel<<<blocks(Nf / 8, B256), B256, 0, stream>>>(users, items, A0, nu * D, Nf / 8);

    // 4. propagation: wave per node; L1..L3 bf16; layer 4 fused with final
    //    combine -> f32 d_out
    const int ggrid = blocks(N, B256 / 64);
    gather_kernel<0><<<ggrid, B256, 0, stream>>>(row_start, csr, (const uint2*)A0, (uint2*)L1,
                                                 nullptr, nullptr, nullptr, nullptr, nullptr, N, nu);
    gather_kernel<0><<<ggrid, B256, 0, stream>>>(row_start, csr, (const uint2*)L1, (uint2*)L2,
                                                 nullptr, nullptr, nullptr, nullptr, nullptr, N, nu);
    gather_kernel<0><<<ggrid, B256, 0, stream>>>(row_start, csr, (const uint2*)L2, (uint2*)L3,
                                                 nullptr, nullptr, nullptr, nullptr, nullptr, N, nu);
    gather_kernel<1><<<ggrid, B256, 0, stream>>>(row_start, csr, (const uint2*)L3, nullptr,
                                                 users, items, (const uint2*)L1, (const uint2*)L2,
                                                 (float*)d_out, N, nu);
}

// Round 5
// 396.352 us; speedup vs baseline: 1.1662x; 1.0579x over previous
//
#include <hip/hip_runtime.h>
#include <hip/hip_bf16.h>

#define D 64
#define NUM_LAYERS 4
#define TILE 4096
#define EPT 16          // edges per thread in placeA (256 thr * 16 = TILE)
#define BKMAX 320       // max buckets (N <= 163840)

// ---------------- helpers ----------------

__device__ __forceinline__ float bf_lo(unsigned u) { return __uint_as_float(u << 16); }
__device__ __forceinline__ float bf_hi(unsigned u) { return __uint_as_float(u & 0xffff0000u); }
__device__ __forceinline__ unsigned bf_pack(float x, float y) {
    __hip_bfloat16 bx = __float2bfloat16(x);
    __hip_bfloat16 by = __float2bfloat16(y);
    return (unsigned)(*reinterpret_cast<unsigned short*>(&bx))
         | ((unsigned)(*reinterpret_cast<unsigned short*>(&by)) << 16);
}

// ---------------- bucket histogram + scan ----------------
// LDS-only histogram: per-node degrees are NOT computed here — 2M device-scope
// scatter atomics cost ~85us on gfx950 (cross-XCD coherence; measured round 3).
// Degrees stay bucket-local in placeB1's LDS.

__global__ void bhist_kernel(const int* __restrict__ dst, int* __restrict__ bcnt, int E, int nbk) {
    __shared__ int h[BKMAX];
    for (int i = threadIdx.x; i < nbk; i += blockDim.x) h[i] = 0;
    __syncthreads();
    int stride = gridDim.x * blockDim.x;
    int gid = blockIdx.x * blockDim.x + threadIdx.x;
    int E4 = (((size_t)dst & 15) == 0) ? (E >> 2) : 0;
    const int4* dst4 = (const int4*)dst;
    for (int i = gid; i < E4; i += stride) {
        int4 d = dst4[i];
        atomicAdd(&h[d.x >> 9], 1);
        atomicAdd(&h[d.y >> 9], 1);
        atomicAdd(&h[d.z >> 9], 1);
        atomicAdd(&h[d.w >> 9], 1);
    }
    for (int e = (E4 << 2) + gid; e < E; e += stride)
        atomicAdd(&h[dst[e] >> 9], 1);
    __syncthreads();
    for (int i = threadIdx.x; i < nbk; i += blockDim.x)
        if (h[i] > 0) atomicAdd(&bcnt[i], h[i]);
}

// single block: exclusive scan of bucket counts -> bstart, gcur
__global__ __launch_bounds__(512) void bscan_kernel(const int* __restrict__ bcnt,
                                                    int* __restrict__ bstart,
                                                    int* __restrict__ gcur, int nbk, int E) {
    __shared__ int sm[512];
    int t = threadIdx.x;
    int v = (t < nbk) ? bcnt[t] : 0;
    sm[t] = v;
    __syncthreads();
    for (int ofs = 1; ofs < 512; ofs <<= 1) {
        int x = (t >= ofs) ? sm[t - ofs] : 0;
        __syncthreads();
        sm[t] += x;
        __syncthreads();
    }
    int excl = sm[t] - v;
    if (t < nbk) { bstart[t] = excl; gcur[t] = excl; }
    if (t == 0) bstart[nbk] = E;
}

// ---------------- place: two-phase tile-partitioned counting sort ----------------

// Pass A: tile -> bucket-sorted mid. Payload: src | (dst&511)<<18  (27 bits, 4B)
__global__ __launch_bounds__(256) void placeA_kernel(const int* __restrict__ src,
                                                     const int* __restrict__ dst,
                                                     int* __restrict__ gcur,
                                                     int* __restrict__ mid,
                                                     int E, int nbk) {
    __shared__ int hist[BKMAX];
    __shared__ int gbase[BKMAX];
    int t = threadIdx.x;
    int tile0 = blockIdx.x * TILE;
    for (int i = t; i < nbk; i += 256) hist[i] = 0;
    __syncthreads();

    bool al = (((size_t)src & 15) == 0) && (((size_t)dst & 15) == 0);

    int p_[EPT];
    int b_[EPT];
    int r_[EPT];
#pragma unroll
    for (int i4 = 0; i4 < 4; ++i4) {
        int e0 = tile0 + i4 * 1024 + t * 4;   // thread handles 4 consecutive edges
        int4 s4, d4;
        if (al && (e0 + 3 < E)) {
            s4 = *(const int4*)(src + e0);
            d4 = *(const int4*)(dst + e0);
        } else {
            s4 = make_int4(0, 0, 0, 0); d4 = make_int4(0, 0, 0, 0);
            if (e0     < E) { s4.x = src[e0];     d4.x = dst[e0]; }
            if (e0 + 1 < E) { s4.y = src[e0 + 1]; d4.y = dst[e0 + 1]; }
            if (e0 + 2 < E) { s4.z = src[e0 + 2]; d4.z = dst[e0 + 2]; }
            if (e0 + 3 < E) { s4.w = src[e0 + 3]; d4.w = dst[e0 + 3]; }
        }
        int ss[4] = { s4.x, s4.y, s4.z, s4.w };
        int dd[4] = { d4.x, d4.y, d4.z, d4.w };
#pragma unroll
        for (int k = 0; k < 4; ++k) {
            int i = i4 * 4 + k;
            int e = e0 + k;
            b_[i] = -1;
            if (e < E) {
                p_[i] = ss[k] | ((dd[k] & 511) << 18);
                b_[i] = dd[k] >> 9;
                r_[i] = atomicAdd(&hist[b_[i]], 1);
            }
        }
    }
    __syncthreads();
    for (int b = t; b < nbk; b += 256) {
        int h = hist[b];
        gbase[b] = (h > 0) ? atomicAdd(&gcur[b], h) : 0;
    }
    __syncthreads();
#pragma unroll
    for (int i = 0; i < EPT; ++i) {
        if (b_[i] >= 0) mid[gbase[b_[i]] + r_[i]] = p_[i];
    }
}

// Pass B1: one block per bucket; per-node degree count in LDS, LDS scan ->
// row_start + deg_inv_sqrt for this bucket's 512 nodes.
__global__ __launch_bounds__(512) void placeB1_kernel(const int* __restrict__ bstart,
                                                      const int* __restrict__ mid,
                                                      int* __restrict__ row_start,
                                                      float* __restrict__ dis,
                                                      int N, int nbk, int E) {
    __shared__ int degsm[512];
    __shared__ int sc[512];
    int b = blockIdx.x;
    int t = threadIdx.x;
    int node0 = b << 9;
    int lo = bstart[b], hi = bstart[b + 1];
    degsm[t] = 0;
    __syncthreads();
    for (int e = lo + t; e < hi; e += 512)
        atomicAdd(&degsm[(mid[e] >> 18) & 511], 1);
    __syncthreads();
    int d = degsm[t];
    sc[t] = d;
    __syncthreads();
    for (int ofs = 1; ofs < 512; ofs <<= 1) {
        int x = (t >= ofs) ? sc[t - ofs] : 0;
        __syncthreads();
        sc[t] += x;
        __syncthreads();
    }
    int excl = sc[t] - d;
    int node = node0 + t;
    if (node < N) {
        row_start[node] = lo + excl;
        dis[node] = (d > 0) ? rsqrtf((float)d) : 0.0f;
    }
    if (b == nbk - 1 && t == 0) row_start[N] = E;
}

// Pass B2: scatter within bucket; compute w = dis[src]*dis[dst] once here.
__global__ __launch_bounds__(512) void placeB2_kernel(const int* __restrict__ bstart,
                                                      const int* __restrict__ mid,
                                                      const int* __restrict__ row_start,
                                                      const float* __restrict__ dis,
                                                      int2* __restrict__ csr, int N) {
    __shared__ int cur[512];
    __shared__ float dloc[512];
    int b = blockIdx.x;
    int t = threadIdx.x;
    int node0 = b << 9;
    int node = node0 + t;
    if (node < N) { cur[t] = row_start[node]; dloc[t] = dis[node]; }
    else          { cur[t] = 0; dloc[t] = 0.0f; }
    __syncthreads();
    int lo = bstart[b], hi = bstart[b + 1];
    for (int e = lo + t; e < hi; e += 512) {
        int m = mid[e];
        int l = (m >> 18) & 511;
        int s = m & 0x3FFFF;
        float w = dis[s] * dloc[l];
        int slot = atomicAdd(&cur[l], 1);
        csr[slot] = make_int2(s, __float_as_int(w));
    }
}

// ---------------- propagation ----------------

// 8 floats per thread: 2x float4 in, 1x uint4 (8 bf16) out.
__global__ void init_kernel(const float* __restrict__ users, const float* __restrict__ items,
                            unsigned* __restrict__ A, int nu_elems, int total8) {
    int i = blockIdx.x * blockDim.x + threadIdx.x;   // bf16x8 group index
    if (i >= total8) return;
    long long base = (long long)i * 8;
    const float4* p;
    if (base < nu_elems) p = (const float4*)users + (base >> 2);
    else                 p = (const float4*)items + ((base - nu_elems) >> 2);
    float4 a = p[0];
    float4 b = p[1];
    uint4 r;
    r.x = bf_pack(a.x, a.y);
    r.y = bf_pack(a.z, a.w);
    r.z = bf_pack(b.x, b.y);
    r.w = bf_pack(b.z, b.w);
    ((uint4*)A)[i] = r;
}

// One wave per dst node, quarter-wave per edge: q = lane>>4 picks the edge,
// c = lane&15 picks the bf16x4 (8B) chunk of the 128B row. 8 edges per iter.
// NOTE: plain cached loads throughout — nt hint on the csr load (round 4)
// cost +6us/dispatch: it sits at the head of the csr->shfl->gather dep chain.
template <int FINAL>
__global__ void gather_kernel(const int* __restrict__ row_start,
                              const int2* __restrict__ csr,
                              const uint2* __restrict__ Au,
                              uint2* __restrict__ Bu,
                              const float* __restrict__ users, const float* __restrict__ items,
                              const uint2* __restrict__ L1u, const uint2* __restrict__ L2u,
                              float* __restrict__ out,
                              int N, int nu) {
    int node = (blockIdx.x * blockDim.x + threadIdx.x) >> 6;
    if (node >= N) return;
    int lane = threadIdx.x & 63;
    int q = lane >> 4;
    int c = lane & 15;
    int beg = row_start[node];
    int end = row_start[node + 1];
    int deg = end - beg;
    float ax = 0.0f, ay = 0.0f, az = 0.0f, aw = 0.0f;

    for (int base = 0; base < deg; base += 64) {
        int chunk = min(64, deg - base);
        int   sl = 0;
        float wl = 0.0f;
        if (lane < chunk) {
            int2 e = csr[beg + base + lane];
            sl = e.x;
            wl = __int_as_float(e.y);
        }
        int k = 0;
        for (; k + 8 <= chunk; k += 8) {
            int i0 = k + q, i1 = k + 4 + q;
            int   s0 = __shfl(sl, i0), s1 = __shfl(sl, i1);
            float w0 = __shfl(wl, i0), w1 = __shfl(wl, i1);
            uint2 u0 = Au[(size_t)s0 * 16 + c];
            uint2 u1 = Au[(size_t)s1 * 16 + c];
            ax += w0 * bf_lo(u0.x); ay += w0 * bf_hi(u0.x);
            az += w0 * bf_lo(u0.y); aw += w0 * bf_hi(u0.y);
            ax += w1 * bf_lo(u1.x); ay += w1 * bf_hi(u1.x);
            az += w1 * bf_lo(u1.y); aw += w1 * bf_hi(u1.y);
        }
        for (; k < chunk; k += 4) {
            int i0 = k + q;
            int   s = __shfl(sl, i0);
            float w = __shfl(wl, i0);
            uint2 u = Au[(size_t)s * 16 + c];
            ax += w * bf_lo(u.x); ay += w * bf_hi(u.x);
            az += w * bf_lo(u.y); aw += w * bf_hi(u.y);
        }
    }

    ax += __shfl_xor(ax, 16); ay += __shfl_xor(ay, 16);
    az += __shfl_xor(az, 16); aw += __shfl_xor(aw, 16);
    ax += __shfl_xor(ax, 32); ay += __shfl_xor(ay, 32);
    az += __shfl_xor(az, 32); aw += __shfl_xor(aw, 32);

    if (q == 0) {
        size_t ro = (size_t)node * 16 + c;
        if (FINAL) {
            uint2 l1 = L1u[ro], l2 = L2u[ro], l3 = Au[ro];
            float4 e0;
            if (node < nu) e0 = ((const float4*)users)[ro];
            else           e0 = ((const float4*)items)[(size_t)(node - nu) * 16 + c];
            float rx = (e0.x + bf_lo(l1.x) + bf_lo(l2.x) + bf_lo(l3.x) + ax) * 0.04f;
            float ry = (e0.y + bf_hi(l1.x) + bf_hi(l2.x) + bf_hi(l3.x) + ay) * 0.04f;
            float rz = (e0.z + bf_lo(l1.y) + bf_lo(l2.y) + bf_lo(l3.y) + az) * 0.04f;
            float rw = (e0.w + bf_hi(l1.y) + bf_hi(l2.y) + bf_hi(l3.y) + aw) * 0.04f;
            ((float4*)out)[ro] = make_float4(rx, ry, rz, rw);
        } else {
            uint2 p;
            p.x = bf_pack(ax, ay);
            p.y = bf_pack(az, aw);
            Bu[ro] = p;
        }
    }
}

// ---------------- launch ----------------

extern "C" void kernel_launch(void* const* d_in, const int* in_sizes, int n_in,
                              void* d_out, int out_size, void* d_ws, size_t ws_size,
                              hipStream_t stream) {
    const float* users = (const float*)d_in[0];
    const float* items = (const float*)d_in[1];
    const int*   eidx  = (const int*)d_in[2];

    const int nu = in_sizes[0] / D;    // 100000
    const int ni = in_sizes[1] / D;    // 50000
    const int N  = nu + ni;            // 150000
    const int E  = in_sizes[2] / 2;    // 2000000
    const int Nf = N * D;              // 9.6M elems
    const int nbk = (N + 511) >> 9;    // 293 buckets

    const int* src = eidx;
    const int* dst = eidx + E;

    char* ws = (char*)d_ws;
    size_t off = 0;
    auto alloc = [&](size_t bytes) {
        char* p = ws + off;
        off += (bytes + 255) & ~(size_t)255;
        return p;
    };
    float* dis       = (float*)alloc((size_t)N * 4);
    int*   row_start = (int*)alloc((size_t)(N + 1) * 4);
    int*   bcnt      = (int*)alloc(BKMAX * 4);
    int*   bstart    = (int*)alloc((BKMAX + 1) * 4);
    int*   gcur      = (int*)alloc(BKMAX * 4);
    int2*  csr       = (int2*)alloc((size_t)E * 8);
    unsigned* A0 = (unsigned*)alloc((size_t)Nf * 2);
    unsigned* L1 = (unsigned*)alloc((size_t)Nf * 2);
    unsigned* L2 = (unsigned*)alloc((size_t)Nf * 2);
    unsigned* L3 = (unsigned*)alloc((size_t)Nf * 2);
    int* mid = (int*)L3;   // alias: mid (E*4B) consumed before L3 is written (gather #3)

    const int B256 = 256;
    auto blocks = [](long long n, int b) { return (int)((n + b - 1) / b); };

    // 1. bucket histogram + bucket scan
    hipMemsetAsync(bcnt, 0, BKMAX * 4, stream);
    bhist_kernel<<<1024, B256, 0, stream>>>(dst, bcnt, E, nbk);
    bscan_kernel<<<1, 512, 0, stream>>>(bcnt, bstart, gcur, nbk, E);

    // 2. place: tile-partition into buckets (4B payload), then per-bucket
    //    degree count + scan (B1) and weighted scatter (B2)
    placeA_kernel<<<blocks(E, TILE), B256, 0, stream>>>(src, dst, gcur, mid, E, nbk);
    placeB1_kernel<<<nbk, 512, 0, stream>>>(bstart, mid, row_start, dis, N, nbk, E);
    placeB2_kernel<<<nbk, 512, 0, stream>>>(bstart, mid, row_start, dis, csr, N);

    // 3. init bf16 A0
    init_kernel<<<blocks(Nf / 8, B256), B256, 0, stream>>>(users, items, A0, nu * D, Nf / 8);

    // 4. propagation: wave per node; L1..L3 bf16; layer 4 fused with final
    //    combine -> f32 d_out
    const int ggrid = blocks(N, B256 / 64);
    gather_kernel<0><<<ggrid, B256, 0, stream>>>(row_start, csr, (const uint2*)A0, (uint2*)L1,
                                                 nullptr, nullptr, nullptr, nullptr, nullptr, N, nu);
    gather_kernel<0><<<ggrid, B256, 0, stream>>>(row_start, csr, (const uint2*)L1, (uint2*)L2,
                                                 nullptr, nullptr, nullptr, nullptr, nullptr, N, nu);
    gather_kernel<0><<<ggrid, B256, 0, stream>>>(row_start, csr, (const uint2*)L2, (uint2*)L3,
                                                 nullptr, nullptr, nullptr, nullptr, nullptr, N, nu);
    gather_kernel<1><<<ggrid, B256, 0, stream>>>(row_start, csr, (const uint2*)L3, nullptr,
                                                 users, items, (const uint2*)L1, (const uint2*)L2,
                                                 (float*)d_out, N, nu);
}

// Round 7
// 390.632 us; speedup vs baseline: 1.1833x; 1.0146x over previous
//
#include <hip/hip_runtime.h>
#include <hip/hip_bf16.h>

#define D 64
#define NUM_LAYERS 4
#define TILE 4096
#define BKMAX 320       // max buckets (N <= 163840)

// ---------------- helpers ----------------

__device__ __forceinline__ float bf_lo(unsigned u) { return __uint_as_float(u << 16); }
__device__ __forceinline__ float bf_hi(unsigned u) { return __uint_as_float(u & 0xffff0000u); }
__device__ __forceinline__ unsigned bf_pack(float x, float y) {
    __hip_bfloat16 bx = __float2bfloat16(x);
    __hip_bfloat16 by = __float2bfloat16(y);
    return (unsigned)(*reinterpret_cast<unsigned short*>(&bx))
         | ((unsigned)(*reinterpret_cast<unsigned short*>(&by)) << 16);
}

// ---------------- bucket histogram + scan ----------------
// LDS-only histogram: per-node degrees are NOT computed here — 2M device-scope
// scatter atomics cost ~85us on gfx950 (cross-XCD coherence; measured round 3).
// Degrees stay bucket-local in placeB1's LDS.

__global__ void bhist_kernel(const int* __restrict__ dst, int* __restrict__ bcnt, int E, int nbk) {
    __shared__ int h[BKMAX];
    for (int i = threadIdx.x; i < nbk; i += blockDim.x) h[i] = 0;
    __syncthreads();
    int stride = gridDim.x * blockDim.x;
    int gid = blockIdx.x * blockDim.x + threadIdx.x;
    int E4 = (((size_t)dst & 15) == 0) ? (E >> 2) : 0;
    const int4* dst4 = (const int4*)dst;
    for (int i = gid; i < E4; i += stride) {
        int4 d = dst4[i];
        atomicAdd(&h[d.x >> 9], 1);
        atomicAdd(&h[d.y >> 9], 1);
        atomicAdd(&h[d.z >> 9], 1);
        atomicAdd(&h[d.w >> 9], 1);
    }
    for (int e = (E4 << 2) + gid; e < E; e += stride)
        atomicAdd(&h[dst[e] >> 9], 1);
    __syncthreads();
    for (int i = threadIdx.x; i < nbk; i += blockDim.x)
        if (h[i] > 0) atomicAdd(&bcnt[i], h[i]);
}

// single block: exclusive scan of bucket counts -> bstart, gcur
__global__ __launch_bounds__(512) void bscan_kernel(const int* __restrict__ bcnt,
                                                    int* __restrict__ bstart,
                                                    int* __restrict__ gcur, int nbk, int E) {
    __shared__ int sm[512];
    int t = threadIdx.x;
    int v = (t < nbk) ? bcnt[t] : 0;
    sm[t] = v;
    __syncthreads();
    for (int ofs = 1; ofs < 512; ofs <<= 1) {
        int x = (t >= ofs) ? sm[t - ofs] : 0;
        __syncthreads();
        sm[t] += x;
        __syncthreads();
    }
    int excl = sm[t] - v;
    if (t < nbk) { bstart[t] = excl; gcur[t] = excl; }
    if (t == 0) bstart[nbk] = E;
}

// ---------------- place: two-phase tile-partitioned counting sort ----------------

// Pass A: tile -> bucket-sorted mid. Payload: src | (dst&511)<<18  (27 bits, 4B).
// LDS-staged scatter: rank edges into a 16KB LDS tile sorted by bucket, then
// drain in POSITION order so global mid-writes are sequential runs per bucket
// (the naive per-rank 4B global scatter touches ~1 line per edge: ~128MB RFO).
__global__ __launch_bounds__(512) void placeA_kernel(const int* __restrict__ src,
                                                     const int* __restrict__ dst,
                                                     int* __restrict__ gcur,
                                                     int* __restrict__ mid,
                                                     int E, int nbk) {
    __shared__ int hist[BKMAX];
    __shared__ int toff[BKMAX];
    __shared__ int gbase[BKMAX];
    __shared__ int sc[512];
    __shared__ int els[TILE];
    __shared__ unsigned short bkt[TILE];
    int t = threadIdx.x;
    int tile0 = blockIdx.x * TILE;
    int tcnt = min(TILE, E - tile0);
    for (int i = t; i < nbk; i += 512) hist[i] = 0;
    __syncthreads();

    bool al = (((size_t)src & 15) == 0) && (((size_t)dst & 15) == 0);

    int p_[8];
    int b_[8];
    int r_[8];
#pragma unroll
    for (int i4 = 0; i4 < 2; ++i4) {
        int e0 = tile0 + i4 * 2048 + t * 4;   // thread handles 4 consecutive edges
        int4 s4, d4;
        if (al && (e0 + 3 < E)) {
            s4 = *(const int4*)(src + e0);
            d4 = *(const int4*)(dst + e0);
        } else {
            s4 = make_int4(0, 0, 0, 0); d4 = make_int4(0, 0, 0, 0);
            if (e0     < E) { s4.x = src[e0];     d4.x = dst[e0]; }
            if (e0 + 1 < E) { s4.y = src[e0 + 1]; d4.y = dst[e0 + 1]; }
            if (e0 + 2 < E) { s4.z = src[e0 + 2]; d4.z = dst[e0 + 2]; }
            if (e0 + 3 < E) { s4.w = src[e0 + 3]; d4.w = dst[e0 + 3]; }
        }
        int ss[4] = { s4.x, s4.y, s4.z, s4.w };
        int dd[4] = { d4.x, d4.y, d4.z, d4.w };
#pragma unroll
        for (int k = 0; k < 4; ++k) {
            int i = i4 * 4 + k;
            int e = e0 + k;
            b_[i] = -1;
            if (e < E) {
                p_[i] = ss[k] | ((dd[k] & 511) << 18);
                b_[i] = dd[k] >> 9;
                r_[i] = atomicAdd(&hist[b_[i]], 1);
            }
        }
    }
    __syncthreads();
    // exclusive scan of hist -> tile-local bucket offsets
    int v = (t < nbk) ? hist[t] : 0;
    sc[t] = v;
    __syncthreads();
    for (int ofs = 1; ofs < 512; ofs <<= 1) {
        int x = (t >= ofs) ? sc[t - ofs] : 0;
        __syncthreads();
        sc[t] += x;
        __syncthreads();
    }
    if (t < nbk) toff[t] = sc[t] - v;
    __syncthreads();
    // scatter into LDS (bucket-sorted positions), record position->bucket
#pragma unroll
    for (int i = 0; i < 8; ++i) {
        if (b_[i] >= 0) {
            int pos = toff[b_[i]] + r_[i];
            els[pos] = p_[i];
            bkt[pos] = (unsigned short)b_[i];
        }
    }
    // reserve global ranges
    for (int b = t; b < nbk; b += 512) {
        int h = hist[b];
        gbase[b] = (h > 0) ? atomicAdd(&gcur[b], h) : 0;
    }
    __syncthreads();
    // drain LDS in position order -> sequential runs per bucket
    for (int i = t; i < tcnt; i += 512) {
        int b = bkt[i];
        mid[gbase[b] + (i - toff[b])] = els[i];
    }
}

// Pass B1: one block per bucket; per-node degree count in LDS, LDS scan ->
// row_start + deg_inv_sqrt for this bucket's 512 nodes.
__global__ __launch_bounds__(512) void placeB1_kernel(const int* __restrict__ bstart,
                                                      const int* __restrict__ mid,
                                                      int* __restrict__ row_start,
                                                      float* __restrict__ dis,
                                                      int N, int nbk, int E) {
    __shared__ int degsm[512];
    __shared__ int sc[512];
    int b = blockIdx.x;
    int t = threadIdx.x;
    int node0 = b << 9;
    int lo = bstart[b], hi = bstart[b + 1];
    degsm[t] = 0;
    __syncthreads();
    for (int e = lo + t; e < hi; e += 512)
        atomicAdd(&degsm[(mid[e] >> 18) & 511], 1);
    __syncthreads();
    int d = degsm[t];
    sc[t] = d;
    __syncthreads();
    for (int ofs = 1; ofs < 512; ofs <<= 1) {
        int x = (t >= ofs) ? sc[t - ofs] : 0;
        __syncthreads();
        sc[t] += x;
        __syncthreads();
    }
    int excl = sc[t] - d;
    int node = node0 + t;
    if (node < N) {
        row_start[node] = lo + excl;
        dis[node] = (d > 0) ? rsqrtf((float)d) : 0.0f;
    }
    if (b == nbk - 1 && t == 0) row_start[N] = E;
}

// Pass B2: scatter within bucket; compute w = dis[src]*dis[dst] once here.
__global__ __launch_bounds__(512) void placeB2_kernel(const int* __restrict__ bstart,
                                                      const int* __restrict__ mid,
                                                      const int* __restrict__ row_start,
                                                      const float* __restrict__ dis,
                                                      int2* __restrict__ csr, int N) {
    __shared__ int cur[512];
    __shared__ float dloc[512];
    int b = blockIdx.x;
    int t = threadIdx.x;
    int node0 = b << 9;
    int node = node0 + t;
    if (node < N) { cur[t] = row_start[node]; dloc[t] = dis[node]; }
    else          { cur[t] = 0; dloc[t] = 0.0f; }
    __syncthreads();
    int lo = bstart[b], hi = bstart[b + 1];
    for (int e = lo + t; e < hi; e += 512) {
        int m = mid[e];
        int l = (m >> 18) & 511;
        int s = m & 0x3FFFF;
        float w = dis[s] * dloc[l];
        int slot = atomicAdd(&cur[l], 1);
        csr[slot] = make_int2(s, __float_as_int(w));
    }
}

// ---------------- propagation ----------------

// 8 floats per thread: 2x float4 in, 1x uint4 (8 bf16) out.
__global__ void init_kernel(const float* __restrict__ users, const float* __restrict__ items,
                            unsigned* __restrict__ A, int nu_elems, int total8) {
    int i = blockIdx.x * blockDim.x + threadIdx.x;   // bf16x8 group index
    if (i >= total8) return;
    long long base = (long long)i * 8;
    const float4* p;
    if (base < nu_elems) p = (const float4*)users + (base >> 2);
    else                 p = (const float4*)items + ((base - nu_elems) >> 2);
    float4 a = p[0];
    float4 b = p[1];
    uint4 r;
    r.x = bf_pack(a.x, a.y);
    r.y = bf_pack(a.z, a.w);
    r.z = bf_pack(b.x, b.y);
    r.w = bf_pack(b.z, b.w);
    ((uint4*)A)[i] = r;
}

// One wave per dst node, quarter-wave per edge: q = lane>>4 picks the edge,
// c = lane&15 picks the bf16x4 (8B) chunk of the 128B row. 8 edges per iter.
// NOTE: plain cached loads throughout — nt hint on the csr load (round 4)
// cost +6us/dispatch: it sits at the head of the csr->shfl->gather dep chain.
template <int FINAL>
__global__ void gather_kernel(const int* __restrict__ row_start,
                              const int2* __restrict__ csr,
                              const uint2* __restrict__ Au,
                              uint2* __restrict__ Bu,
                              const float* __restrict__ users, const float* __restrict__ items,
                              const uint2* __restrict__ L1u, const uint2* __restrict__ L2u,
                              float* __restrict__ out,
                              int N, int nu) {
    int node = (blockIdx.x * blockDim.x + threadIdx.x) >> 6;
    if (node >= N) return;
    int lane = threadIdx.x & 63;
    int q = lane >> 4;
    int c = lane & 15;
    int beg = row_start[node];
    int end = row_start[node + 1];
    int deg = end - beg;
    float ax = 0.0f, ay = 0.0f, az = 0.0f, aw = 0.0f;

    for (int base = 0; base < deg; base += 64) {
        int chunk = min(64, deg - base);
        int   sl = 0;
        float wl = 0.0f;
        if (lane < chunk) {
            int2 e = csr[beg + base + lane];
            sl = e.x;
            wl = __int_as_float(e.y);
        }
        int k = 0;
        for (; k + 8 <= chunk; k += 8) {
            int i0 = k + q, i1 = k + 4 + q;
            int   s0 = __shfl(sl, i0), s1 = __shfl(sl, i1);
            float w0 = __shfl(wl, i0), w1 = __shfl(wl, i1);
            uint2 u0 = Au[(size_t)s0 * 16 + c];
            uint2 u1 = Au[(size_t)s1 * 16 + c];
            ax += w0 * bf_lo(u0.x); ay += w0 * bf_hi(u0.x);
            az += w0 * bf_lo(u0.y); aw += w0 * bf_hi(u0.y);
            ax += w1 * bf_lo(u1.x); ay += w1 * bf_hi(u1.x);
            az += w1 * bf_lo(u1.y); aw += w1 * bf_hi(u1.y);
        }
        for (; k < chunk; k += 4) {
            int i0 = k + q;
            int   s = __shfl(sl, i0);
            float w = __shfl(wl, i0);
            uint2 u = Au[(size_t)s * 16 + c];
            ax += w * bf_lo(u.x); ay += w * bf_hi(u.x);
            az += w * bf_lo(u.y); aw += w * bf_hi(u.y);
        }
    }

    ax += __shfl_xor(ax, 16); ay += __shfl_xor(ay, 16);
    az += __shfl_xor(az, 16); aw += __shfl_xor(aw, 16);
    ax += __shfl_xor(ax, 32); ay += __shfl_xor(ay, 32);
    az += __shfl_xor(az, 32); aw += __shfl_xor(aw, 32);

    if (q == 0) {
        size_t ro = (size_t)node * 16 + c;
        if (FINAL) {
            uint2 l1 = L1u[ro], l2 = L2u[ro], l3 = Au[ro];
            float4 e0;
            if (node < nu) e0 = ((const float4*)users)[ro];
            else           e0 = ((const float4*)items)[(size_t)(node - nu) * 16 + c];
            float rx = (e0.x + bf_lo(l1.x) + bf_lo(l2.x) + bf_lo(l3.x) + ax) * 0.04f;
            float ry = (e0.y + bf_hi(l1.x) + bf_hi(l2.x) + bf_hi(l3.x) + ay) * 0.04f;
            float rz = (e0.z + bf_lo(l1.y) + bf_lo(l2.y) + bf_lo(l3.y) + az) * 0.04f;
            float rw = (e0.w + bf_hi(l1.y) + bf_hi(l2.y) + bf_hi(l3.y) + aw) * 0.04f;
            ((float4*)out)[ro] = make_float4(rx, ry, rz, rw);
        } else {
            uint2 p;
            p.x = bf_pack(ax, ay);
            p.y = bf_pack(az, aw);
            Bu[ro] = p;
        }
    }
}

// ---------------- launch ----------------

extern "C" void kernel_launch(void* const* d_in, const int* in_sizes, int n_in,
                              void* d_out, int out_size, void* d_ws, size_t ws_size,
                              hipStream_t stream) {
    const float* users = (const float*)d_in[0];
    const float* items = (const float*)d_in[1];
    const int*   eidx  = (const int*)d_in[2];

    const int nu = in_sizes[0] / D;    // 100000
    const int ni = in_sizes[1] / D;    // 50000
    const int N  = nu + ni;            // 150000
    const int E  = in_sizes[2] / 2;    // 2000000
    const int Nf = N * D;              // 9.6M elems
    const int nbk = (N + 511) >> 9;    // 293 buckets

    const int* src = eidx;
    const int* dst = eidx + E;

    char* ws = (char*)d_ws;
    size_t off = 0;
    auto alloc = [&](size_t bytes) {
        char* p = ws + off;
        off += (bytes + 255) & ~(size_t)255;
        return p;
    };
    float* dis       = (float*)alloc((size_t)N * 4);
    int*   row_start = (int*)alloc((size_t)(N + 1) * 4);
    int*   bcnt      = (int*)alloc(BKMAX * 4);
    int*   bstart    = (int*)alloc((BKMAX + 1) * 4);
    int*   gcur      = (int*)alloc(BKMAX * 4);
    int2*  csr       = (int2*)alloc((size_t)E * 8);
    unsigned* A0 = (unsigned*)alloc((size_t)Nf * 2);
    unsigned* L1 = (unsigned*)alloc((size_t)Nf * 2);
    unsigned* L2 = (unsigned*)alloc((size_t)Nf * 2);
    unsigned* L3 = (unsigned*)alloc((size_t)Nf * 2);
    int* mid = (int*)L3;   // alias: mid (E*4B) consumed before L3 is written (gather #3)

    const int B256 = 256;
    auto blocks = [](long long n, int b) { return (int)((n + b - 1) / b); };

    // 1. bucket histogram + bucket scan
    hipMemsetAsync(bcnt, 0, BKMAX * 4, stream);
    bhist_kernel<<<1024, B256, 0, stream>>>(dst, bcnt, E, nbk);
    bscan_kernel<<<1, 512, 0, stream>>>(bcnt, bstart, gcur, nbk, E);

    // 2. place: tile-partition into buckets (4B payload, LDS-staged coalesced
    //    drain), then per-bucket degree count + scan (B1) and weighted scatter (B2)
    placeA_kernel<<<blocks(E, TILE), 512, 0, stream>>>(src, dst, gcur, mid, E, nbk);
    placeB1_kernel<<<nbk, 512, 0, stream>>>(bstart, mid, row_start, dis, N, nbk, E);
    placeB2_kernel<<<nbk, 512, 0, stream>>>(bstart, mid, row_start, dis, csr, N);

    // 3. init bf16 A0
    init_kernel<<<blocks(Nf / 8, B256), B256, 0, stream>>>(users, items, A0, nu * D, Nf / 8);

    // 4. propagation: wave per node; L1..L3 bf16; layer 4 fused with final
    //    combine -> f32 d_out
    const int ggrid = blocks(N, B256 / 64);
    gather_kernel<0><<<ggrid, B256, 0, stream>>>(row_start, csr, (const uint2*)A0, (uint2*)L1,
                                                 nullptr, nullptr, nullptr, nullptr, nullptr, N, nu);
    gather_kernel<0><<<ggrid, B256, 0, stream>>>(row_start, csr, (const uint2*)L1, (uint2*)L2,
                                                 nullptr, nullptr, nullptr, nullptr, nullptr, N, nu);
    gather_kernel<0><<<ggrid, B256, 0, stream>>>(row_start, csr, (const uint2*)L2, (uint2*)L3,
                                                 nullptr, nullptr, nullptr, nullptr, nullptr, N, nu);
    gather_kernel<1><<<ggrid, B256, 0, stream>>>(row_start, csr, (const uint2*)L3, nullptr,
                                                 users, items, (const uint2*)L1, (const uint2*)L2,
                                                 (float*)d_out, N, nu);
}